// Round 13
// baseline (40.171 us; speedup 1.0000x reference)
//
#include <hip/hip_runtime.h>

typedef float sf16 __attribute__((ext_vector_type(16)));
typedef float sf8  __attribute__((ext_vector_type(8)));

#define BATCH  8
#define NPTS   4096
#define NSLICE 16                 // target-set split per (dir,b)
#define SLICE  (NPTS / NSLICE)    // 256 targets per block
#define TPB1   512                // 8 waves/block, 1 block/CU
#define QPT    8                  // queries per thread (4096 / 512)
#define GRP    8                  // targets per scalar-load group (96 B)

// Stage 1: grid = 2 dirs x 8 batches x 16 target-slices = 256 blocks.
// Round-13 delta: the target panel is read via the SCALAR path
// (s_load_dwordx16/x8 into SGPRs, inline asm — the compiler wouldn't
// scalarize r12's uniform vector loads). The hot loop now contains ZERO
// vector-memory ops: no ds_read, no lgkmcnt-coupled-to-VALU, no LDS, no
// __syncthreads. Target components are SGPR operands of v_fma directly
// (one SGPR per VALU instr — legal); ry is recomputed per target (~11%
// VALU tax, bet: recovers the ~48% VALU idle that tracked memory-op
// latency across r6/r9/r10/r11/r12). -2 folded into queries; rx folded
// into stored partials. Plain coalesced partial-min stores (no atomics).
__global__ __launch_bounds__(TPB1, 2) void chamfer_stage1(
    const float* __restrict__ preds,
    const float* __restrict__ gts,
    float* __restrict__ part,     // [16 db][NSLICE][NPTS]
    float* __restrict__ out)
{
    const int blk   = blockIdx.x;
    const int slice = blk % NSLICE;
    const int db    = blk / NSLICE;    // dir*8 + b
    const int dir   = db >> 3;
    const int b     = db & 7;

    if (blk == 0 && threadIdx.x == 0) out[0] = 0.0f;

    const float* Q = dir ? gts   : preds;   // query set
    const float* T = dir ? preds : gts;     // target set

    // This thread's 8 consecutive queries (24 floats = 6 float4).
    const int q0 = threadIdx.x * QPT;
    const float4* p4 = reinterpret_cast<const float4*>(
        Q + ((size_t)b * NPTS + q0) * 3);
    const float4 v0 = p4[0], v1 = p4[1], v2 = p4[2];
    const float4 v3 = p4[3], v4 = p4[4], v5 = p4[5];

    const float ax0 = v0.x, ay0 = v0.y, az0 = v0.z;
    const float ax1 = v0.w, ay1 = v1.x, az1 = v1.y;
    const float ax2 = v1.z, ay2 = v1.w, az2 = v2.x;
    const float ax3 = v2.y, ay3 = v2.z, az3 = v2.w;
    const float ax4 = v3.x, ay4 = v3.y, az4 = v3.z;
    const float ax5 = v3.w, ay5 = v4.x, az5 = v4.y;
    const float ax6 = v4.z, ay6 = v4.w, az6 = v5.x;
    const float ax7 = v5.y, ay7 = v5.z, az7 = v5.w;

    // ||q||^2 (folded into stored partials) and scaled queries q' = -2q.
    #define PREP(k) \
        const float rx##k = fmaf(ax##k, ax##k, fmaf(ay##k, ay##k, az##k * az##k)); \
        const float qx##k = -2.0f * ax##k; \
        const float qy##k = -2.0f * ay##k; \
        const float qz##k = -2.0f * az##k;
    PREP(0) PREP(1) PREP(2) PREP(3) PREP(4) PREP(5) PREP(6) PREP(7)
    #undef PREP

    // Block's target slice (raw xyz layout, 16B-aligned, uniform pointer).
    const float* tp = T + ((size_t)b * NPTS + slice * SLICE) * 3;

    float m0 = 3.4e38f, m1 = 3.4e38f, m2 = 3.4e38f, m3 = 3.4e38f;
    float m4 = 3.4e38f, m5 = 3.4e38f, m6 = 3.4e38f, m7 = 3.4e38f;

    // e = ry - 2*dot(q,y), two targets a/b per step, v_min3_f32 fusion.
    #define DO2(k) { \
        const float ea = fmaf(qx##k, txa, fmaf(qy##k, tya, fmaf(qz##k, tza, rya))); \
        const float eb = fmaf(qx##k, txb, fmaf(qy##k, tyb, fmaf(qz##k, tzb, ryb))); \
        m##k = fminf(m##k, fminf(ea, eb)); }

    #define PAIR(XA,YA,ZA, XB,YB,ZB) { \
        const float txa = (XA), tya = (YA), tza = (ZA); \
        const float txb = (XB), tyb = (YB), tzb = (ZB); \
        const float rya = fmaf(txa, txa, fmaf(tya, tya, tza * tza)); \
        const float ryb = fmaf(txb, txb, fmaf(tyb, tyb, tzb * tzb)); \
        DO2(0) DO2(1) DO2(2) DO2(3) DO2(4) DO2(5) DO2(6) DO2(7) }

    for (int g = 0; g < SLICE / GRP; ++g) {
        sf16 A;
        sf8  B;
        // 8 targets = 24 floats = 96 B via SMEM. Waitcnt is inside the asm
        // block, before the outputs are live -> no rule-18 hoisting hazard
        // (all consumers have a dataflow dependency on A/B).
        asm volatile(
            "s_load_dwordx16 %0, %2, 0x0\n\t"
            "s_load_dwordx8  %1, %2, 0x40\n\t"
            "s_waitcnt lgkmcnt(0)"
            : "=&s"(A), "=&s"(B)
            : "s"(tp));
        tp += GRP * 3;

        PAIR(A[0],  A[1],  A[2],   A[3],  A[4],  A[5])
        PAIR(A[6],  A[7],  A[8],   A[9],  A[10], A[11])
        PAIR(A[12], A[13], A[14],  A[15], B[0],  B[1])
        PAIR(B[2],  B[3],  B[4],   B[5],  B[6],  B[7])
    }
    #undef PAIR
    #undef DO2

    // Coalesced 32 B/thread store with rx folded in:
    // part[db][slice][q0..q0+7] = partial_min + ||q||^2
    float4* b4 = reinterpret_cast<float4*>(
        part + ((size_t)db * NSLICE + slice) * NPTS + q0);
    b4[0] = make_float4(m0 + rx0, m1 + rx1, m2 + rx2, m3 + rx3);
    b4[1] = make_float4(m4 + rx4, m5 + rx5, m6 + rx6, m7 + rx7);
}

// Stage 2: one thread per query; min over the 16 slice-partials (rx already
// folded in), block-reduce, one atomicAdd per block.
#define TPB2 256
__global__ __launch_bounds__(TPB2) void chamfer_stage2(
    const float* __restrict__ part,
    float* __restrict__ out)
{
    const int g  = blockIdx.x * TPB2 + threadIdx.x;   // [0, 2*8*4096)
    const int db = g >> 12;
    const int q  = g & (NPTS - 1);

    const float* pp = part + (size_t)db * NSLICE * NPTS + q;
    float m = 3.4e38f;
    #pragma unroll
    for (int s = 0; s < NSLICE; ++s)
        m = fminf(m, pp[(size_t)s * NPTS]);

    float s = m;

    #pragma unroll
    for (int off = 32; off > 0; off >>= 1)
        s += __shfl_down(s, off, 64);

    __shared__ float red[TPB2 / 64];
    const int lane = threadIdx.x & 63;
    const int wid  = threadIdx.x >> 6;
    if (lane == 0) red[wid] = s;
    __syncthreads();
    if (threadIdx.x == 0) {
        float t = 0.0f;
        #pragma unroll
        for (int w = 0; w < TPB2 / 64; ++w) t += red[w];
        atomicAdd(out, t);
    }
}

extern "C" void kernel_launch(void* const* d_in, const int* in_sizes, int n_in,
                              void* d_out, int out_size, void* d_ws, size_t ws_size,
                              hipStream_t stream) {
    const float* preds = (const float*)d_in[0];
    const float* gts   = (const float*)d_in[1];
    float* out  = (float*)d_out;
    float* part = (float*)d_ws;   // 16 db x 16 slices x 4096 floats = 4 MiB

    // Only 2 dispatches: stage1 zeroes `out` itself; `part` is fully
    // written by stage 1 before stage 2 reads it — no memsets needed.
    chamfer_stage1<<<dim3(2 * BATCH * NSLICE), TPB1, 0, stream>>>(preds, gts, part, out);
    chamfer_stage2<<<dim3(2 * BATCH * NPTS / TPB2), TPB2, 0, stream>>>(part, out);
}